// Round 7
// baseline (238.247 us; speedup 1.0000x reference)
//
#include <hip/hip_runtime.h>
#include <math.h>

// MinusAttention: score(i,j) = (w.q_i - w.k_j + b)/sqrt(E), causal softmax, @V.
// Softmax cancels the per-row (w.q_i + b) constant -> weights depend only on keys:
//   out[i] = prefix_{j<=i}(e_j * v_j) / prefix_{j<=i}(e_j),  e_j = exp(-(w.k_j)/8).
// Single kernel, decoupled lookback, round-5 failure modes fixed:
//   - 2048 blocks x 256 thr = 8 blocks/CU = exact full residency (no deadlock)
//   - only v_r[8] per wave lives across the wait (round 5 spilled v_r[32])
//   - poll is ONE coalesced relaxed atomic load of <=63 contiguous flags
//   - lookback aggregate sum parallelized across all 4 waves

#define B_   4
#define S_   2048
#define H_   8
#define E_   64
#define BH_  (B_ * H_)
#define CS   32                  // rows per chunk (per block)
#define NC   (S_ / CS)           // 64 chunks per (b,h)
#define NBLK (BH_ * NC)          // 2048 blocks
#define RPW  8                   // rows per wave
#define AST  80                  // aggregate row stride (floats) = 320B, exclusive lines

__global__ __launch_bounds__(256) void k_fused(const float* __restrict__ keys,
                                               const float* __restrict__ values,
                                               const float* __restrict__ w,
                                               float* __restrict__ agg,
                                               int* __restrict__ flags,
                                               float* __restrict__ out) {
    const int blk = blockIdx.x;
    const int bh  = blk / NC, c = blk % NC;
    const int b   = bh / H_,  h = bh % H_;
    const int t   = threadIdx.x, wave = t >> 6, lane = t & 63;
    const int cf  = lane & 15, rq = lane >> 4;

    __shared__ float e_lds[CS];
    __shared__ float wnum[4][E_];
    __shared__ float wd[4];
    __shared__ float pnum4[4][E_];
    __shared__ float pd4[4];

    const size_t rowW = (size_t)b * S_ + (size_t)c * CS + (size_t)wave * RPW;

    // ---- phase 1: scores for this wave's 8 rows ----
    const float4 w4 = reinterpret_cast<const float4*>(w)[cf];
    const float* kb = keys + (rowW * H_ + h) * (size_t)E_;
    #pragma unroll
    for (int g = 0; g < 2; ++g) {
        const int r = g * 4 + rq;
        const float4 kv = *reinterpret_cast<const float4*>(
            kb + (size_t)r * (H_ * E_) + cf * 4);
        float p = kv.x * w4.x + kv.y * w4.y + kv.z * w4.z + kv.w * w4.w;
        p += __shfl_xor(p, 1);
        p += __shfl_xor(p, 2);
        p += __shfl_xor(p, 4);
        p += __shfl_xor(p, 8);
        if (cf == 0) e_lds[wave * RPW + r] = __expf(-p * 0.125f);
    }

    // ---- values for this wave's 8 rows -> registers (reused in downsweep) ----
    const float* vp = values + (rowW * H_ + h) * (size_t)E_ + lane;
    float v_r[RPW];
    #pragma unroll
    for (int j = 0; j < RPW; ++j) v_r[j] = vp[(size_t)j * (H_ * E_)];

    // ---- per-wave partials ----
    float num = 0.f, den = 0.f;
    #pragma unroll
    for (int j = 0; j < RPW; ++j) {
        const float e = e_lds[wave * RPW + j];
        num = fmaf(e, v_r[j], num);
        den += e;
    }
    wnum[wave][lane] = num;
    if (lane == 0) wd[wave] = den;
    __syncthreads();

    // ---- publish block aggregate, then poll predecessors (wave 0) ----
    const int base = bh * NC;
    if (wave == 0) {
        const float bn = wnum[0][lane] + wnum[1][lane] + wnum[2][lane] + wnum[3][lane];
        float* arow = agg + (size_t)blk * AST;
        arow[lane] = bn;
        if (lane == 0) arow[E_] = wd[0] + wd[1] + wd[2] + wd[3];
        __threadfence();                                   // aggregate before flag
        if (lane == 0)
            __hip_atomic_store(&flags[blk], 1, __ATOMIC_RELEASE,
                               __HIP_MEMORY_SCOPE_AGENT);
        if (c > 0) {
            for (;;) {                                     // one coalesced 256B poll
                const int f = (lane < c)
                    ? __hip_atomic_load(&flags[base + lane], __ATOMIC_RELAXED,
                                        __HIP_MEMORY_SCOPE_AGENT)
                    : 1;
                if (__all(f != 0)) break;
                __builtin_amdgcn_s_sleep(2);
            }
        }
    }
    __syncthreads();
    __threadfence();                                       // acquire before agg reads

    // ---- lookback sum, wave-strided over predecessors ----
    float pn = 0.f, pd = 0.f;
    for (int cp = wave; cp < c; cp += 4) {
        const float* prow = agg + (size_t)(base + cp) * AST;
        pn += prow[lane];                                  // 256B coalesced
        pd += prow[E_];                                    // broadcast
    }
    pnum4[wave][lane] = pn;
    if (lane == 0) pd4[wave] = pd;
    __syncthreads();

    // ---- combine + in-block wave prefix + downsweep from registers ----
    float pnum = pnum4[0][lane] + pnum4[1][lane] + pnum4[2][lane] + pnum4[3][lane];
    float pden = pd4[0] + pd4[1] + pd4[2] + pd4[3];
    #pragma unroll
    for (int w2 = 0; w2 < 3; ++w2) {
        if (w2 < wave) { pnum += wnum[w2][lane]; pden += wd[w2]; }
    }

    float* op = out + (rowW * H_ + h) * (size_t)E_ + lane;   // L == S
    #pragma unroll
    for (int j = 0; j < RPW; ++j) {
        const float e = e_lds[wave * RPW + j];
        pnum = fmaf(e, v_r[j], pnum);
        pden += e;
        __builtin_nontemporal_store(pnum * __builtin_amdgcn_rcpf(pden),
                                    &op[(size_t)j * (H_ * E_)]);
    }
}

extern "C" void kernel_launch(void* const* d_in, const int* in_sizes, int n_in,
                              void* d_out, int out_size, void* d_ws, size_t ws_size,
                              hipStream_t stream) {
    // inputs: 0=queries (UNUSED), 1=keys, 2=values, 3=w_score,
    //         4=b_score (cancels), 5=attn_mask (sentinel -> causal)
    const float* keys   = (const float*)d_in[1];
    const float* values = (const float*)d_in[2];
    const float* w      = (const float*)d_in[3];
    float* out = (float*)d_out;

    // workspace: agg[NBLK*AST] floats (655KB) | flags[NBLK] ints (8KB)
    float* agg   = (float*)d_ws;
    int*   flags = (int*)(agg + (size_t)NBLK * AST);

    hipMemsetAsync(flags, 0, NBLK * sizeof(int), stream);   // capturable node
    hipLaunchKernelGGL(k_fused, dim3(NBLK), dim3(256), 0, stream,
                       keys, values, w, agg, flags, out);
}

// Round 9
// 23.321 us; speedup vs baseline: 10.2160x; 10.2160x over previous
//
#include <hip/hip_runtime.h>
#include <math.h>

// MinusAttention: score(i,j) = (w.q_i - w.k_j + b)/sqrt(E), causal softmax, @V.
// Softmax cancels the per-row (w.q_i + b) constant -> weights depend only on keys:
//   out[i] = prefix_{j<=i}(e_j * v_j) / prefix_{j<=i}(e_j),  e_j = exp(-(w.k_j)/8).
// Two kernels (rounds 3/5/7 proved ANY intra-kernel cross-block sync — coop grid
// sync, decoupled lookback, fence+flag polling — costs far more than a launch):
//   K1: chunk (32 rows) scores + chunk-LOCAL inclusive prefix of e*v written
//       straight into `out` (L3-resident), local den prefix, chunk aggregates.
//       V never needs re-reading; K/V loads are non-temporal.
//   K2: featherweight RMW: out = (P + out) * rcp(Q + dloc). float4 in/out.
// 2048 blocks x 256 threads each -> 8 blocks/CU.

#define B_   4
#define S_   2048
#define H_   8
#define E_   64
#define BH_  (B_ * H_)
#define CS   32                  // rows per chunk (per block)
#define NC   (S_ / CS)           // 64 chunks per (b,h)
#define NBLK (BH_ * NC)          // 2048 blocks
#define RPW  8                   // rows per wave

typedef float v4f __attribute__((ext_vector_type(4)));   // NT-builtin-compatible

// ---------------- K1: scores + local prefixes + aggregates ----------------
__global__ __launch_bounds__(256) void k_part(const float* __restrict__ keys,
                                              const float* __restrict__ values,
                                              const float* __restrict__ w,
                                              float* __restrict__ nloc,   // == out
                                              float* __restrict__ dloc,
                                              float* __restrict__ cnum,
                                              float* __restrict__ cden) {
    const int blk = blockIdx.x;
    const int bh  = blk / NC, c = blk % NC;
    const int b   = bh / H_,  h = bh % H_;
    const int t   = threadIdx.x, wave = t >> 6, lane = t & 63;
    const int cf  = lane & 15, rq = lane >> 4;

    __shared__ float e_lds[CS];
    __shared__ float wnum[4][E_];
    __shared__ float wd[4];
    __shared__ float dl[CS];

    const size_t rowW = (size_t)b * S_ + (size_t)c * CS + (size_t)wave * RPW;

    // scores for this wave's 8 rows: e = exp(-(w.k)/8)
    const float4 w4 = reinterpret_cast<const float4*>(w)[cf];
    const float* kb = keys + (rowW * H_ + h) * (size_t)E_;
    #pragma unroll
    for (int g = 0; g < 2; ++g) {
        const int r = g * 4 + rq;
        const v4f kv = __builtin_nontemporal_load(
            reinterpret_cast<const v4f*>(kb + (size_t)r * (H_ * E_)) + cf);
        float p = kv.x * w4.x + kv.y * w4.y + kv.z * w4.z + kv.w * w4.w;
        p += __shfl_xor(p, 1);
        p += __shfl_xor(p, 2);
        p += __shfl_xor(p, 4);
        p += __shfl_xor(p, 8);
        if (cf == 0) e_lds[wave * RPW + r] = __expf(-p * 0.125f);
    }

    // values for this wave's rows -> registers (lane = channel)
    const float* vp = values + (rowW * H_ + h) * (size_t)E_ + lane;
    float v_r[RPW];
    #pragma unroll
    for (int j = 0; j < RPW; ++j)
        v_r[j] = __builtin_nontemporal_load(vp + (size_t)j * (H_ * E_));

    // loop A: per-wave partials (own-wave LDS, no barrier needed)
    float n = 0.f, d = 0.f;
    #pragma unroll
    for (int j = 0; j < RPW; ++j) {
        const float e = e_lds[wave * RPW + j];
        n = fmaf(e, v_r[j], n);
        d += e;
    }
    wnum[wave][lane] = n;
    if (lane == 0) wd[wave] = d;
    __syncthreads();

    // cross-wave offsets within chunk
    float noff = 0.f, doff = 0.f;
    #pragma unroll
    for (int w2 = 0; w2 < 3; ++w2) {
        if (w2 < wave) { noff += wnum[w2][lane]; doff += wd[w2]; }
    }

    // loop B: chunk-local inclusive prefixes -> out (cached: K2 reads these)
    float* np = nloc + (rowW * H_ + h) * (size_t)E_ + lane;
    float nr = noff, dr = doff;
    #pragma unroll
    for (int j = 0; j < RPW; ++j) {
        const float e = e_lds[wave * RPW + j];
        nr = fmaf(e, v_r[j], nr);
        dr += e;
        np[(size_t)j * (H_ * E_)] = nr;
        if (lane == 0) dl[wave * RPW + j] = dr;
    }

    // chunk aggregates
    if (wave == 0) {
        const float cn = wnum[0][lane] + wnum[1][lane] + wnum[2][lane] + wnum[3][lane];
        cnum[(size_t)blk * E_ + lane] = cn;
        if (lane == 0) cden[blk] = wd[0] + wd[1] + wd[2] + wd[3];
    }
    __syncthreads();
    if (t < CS) dloc[(size_t)bh * S_ + (size_t)c * CS + t] = dl[t];
}

// ---------------- K2: prefix offsets + RMW finish ----------------
__global__ __launch_bounds__(256) void k_finish(const float* __restrict__ cnum,
                                                const float* __restrict__ cden,
                                                const float* __restrict__ dloc,
                                                float* __restrict__ out) {
    const int blk = blockIdx.x;
    const int bh  = blk / NC, c = blk % NC;
    const int b   = bh / H_,  h = bh % H_;
    const int t   = threadIdx.x, wave = t >> 6, lane = t & 63;

    __shared__ float pnum4[4][E_];
    __shared__ float pd4[4];
    __shared__ float dl[CS];

    // cross-chunk exclusive prefix, wave-strided over predecessors (L2-hot)
    const int base = bh * NC;
    float pn = 0.f, pd = 0.f;
    for (int cp = wave; cp < c; cp += 4) {
        pn += cnum[(size_t)(base + cp) * E_ + lane];   // 256B coalesced
        pd += cden[base + cp];                         // uniform
    }
    pnum4[wave][lane] = pn;
    if (lane == 0) pd4[wave] = pd;
    if (t < CS) dl[t] = dloc[(size_t)bh * S_ + (size_t)c * CS + t];
    __syncthreads();

    const float q = pd4[0] + pd4[1] + pd4[2] + pd4[3];
    const int rg = t >> 4, c4 = t & 15;
    float P[4];
    #pragma unroll
    for (int k = 0; k < 4; ++k)
        P[k] = pnum4[0][c4 * 4 + k] + pnum4[1][c4 * 4 + k] +
               pnum4[2][c4 * 4 + k] + pnum4[3][c4 * 4 + k];

    // two rows per thread: rg and rg+16
    #pragma unroll
    for (int half = 0; half < 2; ++half) {
        const int r = rg + half * 16;
        v4f* op = reinterpret_cast<v4f*>(
            out + (((size_t)b * S_ + (size_t)c * CS + r) * H_ + h) * (size_t)E_) + c4;
        const v4f nl = *op;                             // L3-hot (written by K1)
        const float ri = __builtin_amdgcn_rcpf(q + dl[r]);
        v4f res;
        res.x = (P[0] + nl.x) * ri;
        res.y = (P[1] + nl.y) * ri;
        res.z = (P[2] + nl.z) * ri;
        res.w = (P[3] + nl.w) * ri;
        __builtin_nontemporal_store(res, op);
    }
}

extern "C" void kernel_launch(void* const* d_in, const int* in_sizes, int n_in,
                              void* d_out, int out_size, void* d_ws, size_t ws_size,
                              hipStream_t stream) {
    // inputs: 0=queries (UNUSED), 1=keys, 2=values, 3=w_score,
    //         4=b_score (cancels), 5=attn_mask (sentinel -> causal)
    const float* keys   = (const float*)d_in[1];
    const float* values = (const float*)d_in[2];
    const float* w      = (const float*)d_in[3];
    float* out = (float*)d_out;

    // workspace (floats): dloc[BH*S] (256KB) | cnum[NBLK*E] (512KB) | cden[NBLK]
    float* dloc = (float*)d_ws;
    float* cnum = dloc + (size_t)BH_ * S_;
    float* cden = cnum + (size_t)NBLK * E_;

    hipLaunchKernelGGL(k_part, dim3(NBLK), dim3(256), 0, stream,
                       keys, values, w, out, dloc, cnum, cden);
    hipLaunchKernelGGL(k_finish, dim3(NBLK), dim3(256), 0, stream,
                       cnum, cden, dloc, out);
}

// Round 10
// 20.803 us; speedup vs baseline: 11.4523x; 1.1210x over previous
//
#include <hip/hip_runtime.h>
#include <math.h>

// MinusAttention: score(i,j) = (w.q_i - w.k_j + b)/sqrt(E), causal softmax, @V.
// Softmax cancels the per-row (w.q_i + b) constant -> weights depend only on keys:
//   out[i] = prefix_{j<=i}(e_j * v_j) / prefix_{j<=i}(e_j),  e_j = exp(-(w.k_j)/8).
// Two kernels (rounds 3/5/7: ANY intra-kernel cross-block sync — coop grid sync,
// decoupled lookback, fence+flag poll — costs more than a second launch).
// Round 9 lesson: write out ONCE; let K2 re-read values from L2/L3.
//   K1: chunk (32 rows) scores + chunk partial sums. Early V loads (T14),
//       NT key loads (read-once; don't evict values from cache).
//   K2: wave-strided prefix over predecessor chunks + LDS-staged V downsweep.
// 2048 blocks x 256 threads -> 8 blocks/CU.

#define B_   4
#define S_   2048
#define H_   8
#define E_   64
#define BH_  (B_ * H_)
#define CS   32                  // rows per chunk (per block)
#define NC   (S_ / CS)           // 64 chunks per (b,h)
#define NBLK (BH_ * NC)          // 2048 blocks
#define RPW  8                   // rows per wave in downsweep

typedef float v4f __attribute__((ext_vector_type(4)));

// ---------------- K1: scores + chunk partials ----------------
__global__ __launch_bounds__(256) void k_part(const float* __restrict__ keys,
                                              const float* __restrict__ values,
                                              const float* __restrict__ w,
                                              float* __restrict__ e_g,
                                              float* __restrict__ cden,
                                              float* __restrict__ cnum) {
    const int blk = blockIdx.x;
    const int bh  = blk / NC, c = blk % NC;
    const int b   = bh / H_,  h = bh % H_;
    const int t   = threadIdx.x, wave = t >> 6, lane = t & 63;
    const int cf  = lane & 15, rq = lane >> 4;
    const int c4  = t & 15,   rg = t >> 4;     // value-load pattern

    __shared__ float e_lds[CS];
    __shared__ float red[16][E_];              // row-group partials, 4KB

    const size_t row0 = (size_t)b * S_ + (size_t)c * CS;

    // T14: issue value loads FIRST — latency hides under the key dots.
    // Rows rg and rg+16, float4 column c4. Cached (K2 re-reads them).
    const v4f* vb = reinterpret_cast<const v4f*>(
        values + (row0 * H_ + h) * (size_t)E_) + c4;
    const v4f v0 = vb[(size_t)rg * (H_ * E_ / 4)];
    const v4f v1 = vb[(size_t)(rg + 16) * (H_ * E_ / 4)];

    // scores: wave w covers rows w*8 .. w*8+7; e = exp(-(w.k)/8).
    // Keys are read-once -> non-temporal (preserve L2/L3 for values).
    const float4 w4 = reinterpret_cast<const float4*>(w)[cf];
    const float* kb = keys + (row0 * H_ + h) * (size_t)E_;
    #pragma unroll
    for (int g = 0; g < 2; ++g) {
        const int r = wave * RPW + g * 4 + rq;
        const v4f kv = __builtin_nontemporal_load(
            reinterpret_cast<const v4f*>(kb + (size_t)r * (H_ * E_)) + cf);
        float p = kv.x * w4.x + kv.y * w4.y + kv.z * w4.z + kv.w * w4.w;
        p += __shfl_xor(p, 1);
        p += __shfl_xor(p, 2);
        p += __shfl_xor(p, 4);
        p += __shfl_xor(p, 8);
        if (cf == 0) e_lds[r] = __expf(-p * 0.125f);
    }
    __syncthreads();

    // weighted rows: acc = e[rg]*v0 + e[rg+16]*v1
    const float e0 = e_lds[rg], e1 = e_lds[rg + 16];
    v4f acc;
    acc.x = fmaf(e1, v1.x, e0 * v0.x);
    acc.y = fmaf(e1, v1.y, e0 * v0.y);
    acc.z = fmaf(e1, v1.z, e0 * v0.z);
    acc.w = fmaf(e1, v1.w, e0 * v0.w);
    *reinterpret_cast<v4f*>(&red[rg][c4 * 4]) = acc;

    // den: butterfly over the 32 e values (wave 0)
    if (wave == 0) {
        float d = (lane < CS) ? e_lds[lane] : 0.f;
        d += __shfl_xor(d, 1);
        d += __shfl_xor(d, 2);
        d += __shfl_xor(d, 4);
        d += __shfl_xor(d, 8);
        d += __shfl_xor(d, 16);
        if (lane == 0) cden[blk] = d;
    }
    __syncthreads();

    if (t < E_) {                              // channel-wise reduce over 16 rg
        float s = 0.f;
        #pragma unroll
        for (int r2 = 0; r2 < 16; ++r2) s += red[r2][t];
        cnum[(size_t)blk * E_ + t] = s;
    }
    if (t < CS) e_g[(size_t)blk * CS + t] = e_lds[t];
}

// ---------------- K2: prefix + LDS-staged downsweep + out ----------------
__global__ __launch_bounds__(256) void k_scan(const float* __restrict__ values,
                                              const float* __restrict__ e_g,
                                              const float* __restrict__ cden,
                                              const float* __restrict__ cnum,
                                              float* __restrict__ out) {
    const int blk = blockIdx.x;
    const int bh  = blk / NC, c = blk % NC;
    const int b   = bh / H_,  h = bh % H_;
    const int t   = threadIdx.x, wave = t >> 6, lane = t & 63;
    const int c4  = t & 15,   rg = t >> 4;

    __shared__ float e_lds[CS];
    __shared__ float v_lds[CS][E_];            // 8KB staged V tile
    __shared__ float pnum4[4][E_];
    __shared__ float wnum[4][E_];
    __shared__ float pd4[4], wd[4];

    const size_t row0 = (size_t)b * S_ + (size_t)c * CS;

    // T14: issue V (float4, L2/L3-hot) + e loads first; prefix loop hides latency.
    const v4f* vb = reinterpret_cast<const v4f*>(
        values + (row0 * H_ + h) * (size_t)E_) + c4;
    const v4f v0 = vb[(size_t)rg * (H_ * E_ / 4)];
    const v4f v1 = vb[(size_t)(rg + 16) * (H_ * E_ / 4)];
    const float ee = (t < CS) ? e_g[(size_t)blk * CS + t] : 0.f;

    // cross-chunk exclusive prefix, wave-strided over predecessors (L2-hot)
    const int base = bh * NC;
    float pn = 0.f, pd = 0.f;
    for (int cp = wave; cp < c; cp += 4) {
        pn += cnum[(size_t)(base + cp) * E_ + lane];   // 256B coalesced
        pd += cden[base + cp];                         // uniform
    }
    pnum4[wave][lane] = pn;
    if (lane == 0) pd4[wave] = pd;

    // stage V + e into LDS
    if (t < CS) e_lds[t] = ee;
    *reinterpret_cast<v4f*>(&v_lds[rg][c4 * 4])      = v0;
    *reinterpret_cast<v4f*>(&v_lds[rg + 16][c4 * 4]) = v1;
    __syncthreads();

    // per-wave partials: wave w owns rows w*8 .. w*8+7 (2-way LDS alias = free)
    float num = 0.f, den = 0.f;
    #pragma unroll
    for (int j = 0; j < RPW; ++j) {
        const float e = e_lds[wave * RPW + j];
        num = fmaf(e, v_lds[wave * RPW + j][lane], num);
        den += e;
    }
    wnum[wave][lane] = num;
    if (lane == 0) wd[wave] = den;
    __syncthreads();

    // combine cross-chunk + cross-wave offsets
    float pnum = pnum4[0][lane] + pnum4[1][lane] + pnum4[2][lane] + pnum4[3][lane];
    float pden = pd4[0] + pd4[1] + pd4[2] + pd4[3];
    #pragma unroll
    for (int w2 = 0; w2 < 3; ++w2) {
        if (w2 < wave) { pnum += wnum[w2][lane]; pden += wd[w2]; }
    }

    // downsweep from LDS, NT store (out is write-once, never re-read)
    float* op = out + ((row0 + wave * RPW) * H_ + h) * (size_t)E_ + lane;  // L==S
    #pragma unroll
    for (int j = 0; j < RPW; ++j) {
        const float e = e_lds[wave * RPW + j];
        pnum = fmaf(e, v_lds[wave * RPW + j][lane], pnum);
        pden += e;
        __builtin_nontemporal_store(pnum * __builtin_amdgcn_rcpf(pden),
                                    &op[(size_t)j * (H_ * E_)]);
    }
}

extern "C" void kernel_launch(void* const* d_in, const int* in_sizes, int n_in,
                              void* d_out, int out_size, void* d_ws, size_t ws_size,
                              hipStream_t stream) {
    // inputs: 0=queries (UNUSED), 1=keys, 2=values, 3=w_score,
    //         4=b_score (cancels), 5=attn_mask (sentinel -> causal)
    const float* keys   = (const float*)d_in[1];
    const float* values = (const float*)d_in[2];
    const float* w      = (const float*)d_in[3];
    float* out = (float*)d_out;

    // workspace (floats): e_g[NBLK*CS] | cnum[NBLK*E] | cden[NBLK]
    float* e_g  = (float*)d_ws;
    float* cnum = e_g + (size_t)NBLK * CS;
    float* cden = cnum + (size_t)NBLK * E_;

    hipLaunchKernelGGL(k_part, dim3(NBLK), dim3(256), 0, stream,
                       keys, values, w, e_g, cden, cnum);
    hipLaunchKernelGGL(k_scan, dim3(NBLK), dim3(256), 0, stream,
                       values, e_g, cden, cnum, out);
}

// Round 11
// 17.140 us; speedup vs baseline: 13.9003x; 1.2138x over previous
//
#include <hip/hip_runtime.h>
#include <math.h>

// MinusAttention: score(i,j) = (w.q_i - w.k_j + b)/sqrt(E), causal softmax, @V.
// Softmax cancels the per-row (w.q_i + b) constant -> weights depend only on keys:
//   out[i] = prefix_{j<=i}(e_j * v_j) / prefix_{j<=i}(e_j),  e_j = exp(-(w.k_j)/8).
// Two kernels (rounds 3/5/7: ANY intra-kernel cross-block sync — coop grid sync,
// decoupled lookback, fence+flag poll — measured 2-12x worse than a 2nd launch).
// Round 9: write out once. Round 10: no LDS V-staging (register downsweep wins).
// This round: CS 32->64 (1024 blocks): 4x less aggregate-prefix traffic, 2x ILP.
//   K1: chunk (64 rows) scores + chunk partial sums. Early V loads, NT key loads.
//   K2: wave-strided prefix over predecessors + register V downsweep + NT out.

#define B_   4
#define S_   2048
#define H_   8
#define E_   64
#define BH_  (B_ * H_)
#define CS   64                  // rows per chunk (per block)
#define NC   (S_ / CS)           // 32 chunks per (b,h)
#define NBLK (BH_ * NC)          // 1024 blocks
#define RPW  16                  // rows per wave in downsweep (CS / 4 waves)

typedef float v4f __attribute__((ext_vector_type(4)));

// ---------------- K1: scores + chunk partials ----------------
__global__ __launch_bounds__(256) void k_part(const float* __restrict__ keys,
                                              const float* __restrict__ values,
                                              const float* __restrict__ w,
                                              float* __restrict__ e_g,
                                              float* __restrict__ cden,
                                              float* __restrict__ cnum) {
    const int blk = blockIdx.x;
    const int bh  = blk / NC, c = blk % NC;
    const int b   = bh / H_,  h = bh % H_;
    const int t   = threadIdx.x, wave = t >> 6, lane = t & 63;
    const int cf  = lane & 15, rq = lane >> 4;
    const int c4  = t & 15,   rg = t >> 4;     // value-load pattern (16 row-groups)

    __shared__ float e_lds[CS];
    __shared__ float red[16][E_];              // row-group partials, 4KB

    const size_t row0 = (size_t)b * S_ + (size_t)c * CS;

    // T14: issue the 4 independent V float4 streams FIRST (latency hides under
    // key dots). Rows rg+16k, float4 column c4. Cached — K2 re-reads them.
    const v4f* vb = reinterpret_cast<const v4f*>(
        values + (row0 * H_ + h) * (size_t)E_) + c4;
    v4f v0 = vb[(size_t)(rg     ) * (H_ * E_ / 4)];
    v4f v1 = vb[(size_t)(rg + 16) * (H_ * E_ / 4)];
    v4f v2 = vb[(size_t)(rg + 32) * (H_ * E_ / 4)];
    v4f v3 = vb[(size_t)(rg + 48) * (H_ * E_ / 4)];

    // scores: wave w covers rows w*16 .. w*16+15; e = exp(-(w.k)/8).
    // Keys are read-once -> non-temporal (preserve L2/L3 for values).
    const float4 w4 = reinterpret_cast<const float4*>(w)[cf];
    const float* kb = keys + (row0 * H_ + h) * (size_t)E_;
    #pragma unroll
    for (int g = 0; g < 4; ++g) {
        const int r = wave * RPW + g * 4 + rq;
        const v4f kv = __builtin_nontemporal_load(
            reinterpret_cast<const v4f*>(kb + (size_t)r * (H_ * E_)) + cf);
        float p = kv.x * w4.x + kv.y * w4.y + kv.z * w4.z + kv.w * w4.w;
        p += __shfl_xor(p, 1);
        p += __shfl_xor(p, 2);
        p += __shfl_xor(p, 4);
        p += __shfl_xor(p, 8);
        if (cf == 0) e_lds[r] = __expf(-p * 0.125f);
    }
    __syncthreads();

    // weighted rows: acc = sum_k e[rg+16k] * vk
    const float e0 = e_lds[rg], e1 = e_lds[rg + 16];
    const float e2 = e_lds[rg + 32], e3 = e_lds[rg + 48];
    v4f acc;
    acc.x = fmaf(e3, v3.x, fmaf(e2, v2.x, fmaf(e1, v1.x, e0 * v0.x)));
    acc.y = fmaf(e3, v3.y, fmaf(e2, v2.y, fmaf(e1, v1.y, e0 * v0.y)));
    acc.z = fmaf(e3, v3.z, fmaf(e2, v2.z, fmaf(e1, v1.z, e0 * v0.z)));
    acc.w = fmaf(e3, v3.w, fmaf(e2, v2.w, fmaf(e1, v1.w, e0 * v0.w)));
    *reinterpret_cast<v4f*>(&red[rg][c4 * 4]) = acc;

    // den: full 64-lane butterfly over e (wave 0)
    if (wave == 0) {
        float d = e_lds[lane];
        d += __shfl_xor(d, 1);
        d += __shfl_xor(d, 2);
        d += __shfl_xor(d, 4);
        d += __shfl_xor(d, 8);
        d += __shfl_xor(d, 16);
        d += __shfl_xor(d, 32);
        if (lane == 0) cden[blk] = d;
    }
    __syncthreads();

    if (t < E_) {                              // channel-wise reduce over 16 rg
        float s = 0.f;
        #pragma unroll
        for (int r2 = 0; r2 < 16; ++r2) s += red[r2][t];
        cnum[(size_t)blk * E_ + t] = s;
    }
    if (t < CS) e_g[(size_t)blk * CS + t] = e_lds[t];
}

// ---------------- K2: prefix + register downsweep + out ----------------
__global__ __launch_bounds__(256) void k_scan(const float* __restrict__ values,
                                              const float* __restrict__ e_g,
                                              const float* __restrict__ cden,
                                              const float* __restrict__ cnum,
                                              float* __restrict__ out) {
    const int blk = blockIdx.x;
    const int bh  = blk / NC, c = blk % NC;
    const int b   = bh / H_,  h = bh % H_;
    const int t   = threadIdx.x, wave = t >> 6, lane = t & 63;

    __shared__ float e_lds[CS];
    __shared__ float pnum4[4][E_];
    __shared__ float wnum[4][E_];
    __shared__ float pd4[4], wd[4];

    const size_t row0 = (size_t)b * S_ + (size_t)c * CS;

    // T14: issue V (L2/L3-hot, 16-deep queue) + e loads first.
    const float* vp = values + ((row0 + wave * RPW) * H_ + h) * (size_t)E_ + lane;
    float v_r[RPW];
    #pragma unroll
    for (int j = 0; j < RPW; ++j) v_r[j] = vp[(size_t)j * (H_ * E_)];
    if (t < CS) e_lds[t] = e_g[(size_t)blk * CS + t];

    // cross-chunk exclusive prefix, wave-strided over predecessors (L2-hot)
    const int base = bh * NC;
    float pn = 0.f, pd = 0.f;
    for (int cp = wave; cp < c; cp += 4) {
        pn += cnum[(size_t)(base + cp) * E_ + lane];   // 256B coalesced
        pd += cden[base + cp];                         // uniform
    }
    pnum4[wave][lane] = pn;
    if (lane == 0) pd4[wave] = pd;
    __syncthreads();

    // per-wave partials: wave w owns rows w*16 .. w*16+15
    float num = 0.f, den = 0.f;
    #pragma unroll
    for (int j = 0; j < RPW; ++j) {
        const float e = e_lds[wave * RPW + j];
        num = fmaf(e, v_r[j], num);
        den += e;
    }
    wnum[wave][lane] = num;
    if (lane == 0) wd[wave] = den;
    __syncthreads();

    // combine cross-chunk + cross-wave offsets
    float pnum = pnum4[0][lane] + pnum4[1][lane] + pnum4[2][lane] + pnum4[3][lane];
    float pden = pd4[0] + pd4[1] + pd4[2] + pd4[3];
    #pragma unroll
    for (int w2 = 0; w2 < 3; ++w2) {
        if (w2 < wave) { pnum += wnum[w2][lane]; pden += wd[w2]; }
    }

    // downsweep from registers, NT store (out is write-once)
    float* op = out + ((row0 + wave * RPW) * H_ + h) * (size_t)E_ + lane;  // L==S
    #pragma unroll
    for (int j = 0; j < RPW; ++j) {
        const float e = e_lds[wave * RPW + j];
        pnum = fmaf(e, v_r[j], pnum);
        pden += e;
        __builtin_nontemporal_store(pnum * __builtin_amdgcn_rcpf(pden),
                                    &op[(size_t)j * (H_ * E_)]);
    }
}

extern "C" void kernel_launch(void* const* d_in, const int* in_sizes, int n_in,
                              void* d_out, int out_size, void* d_ws, size_t ws_size,
                              hipStream_t stream) {
    // inputs: 0=queries (UNUSED), 1=keys, 2=values, 3=w_score,
    //         4=b_score (cancels), 5=attn_mask (sentinel -> causal)
    const float* keys   = (const float*)d_in[1];
    const float* values = (const float*)d_in[2];
    const float* w      = (const float*)d_in[3];
    float* out = (float*)d_out;

    // workspace (floats): e_g[NBLK*CS] | cnum[NBLK*E] | cden[NBLK]
    float* e_g  = (float*)d_ws;
    float* cnum = e_g + (size_t)NBLK * CS;
    float* cden = cnum + (size_t)NBLK * E_;

    hipLaunchKernelGGL(k_part, dim3(NBLK), dim3(256), 0, stream,
                       keys, values, w, e_g, cden, cnum);
    hipLaunchKernelGGL(k_scan, dim3(NBLK), dim3(256), 0, stream,
                       values, e_g, cden, cnum, out);
}

// Round 12
// 15.789 us; speedup vs baseline: 15.0893x; 1.0855x over previous
//
#include <hip/hip_runtime.h>
#include <math.h>

// MinusAttention: score(i,j) = (w.q_i - w.k_j + b)/sqrt(E), causal softmax, @V.
// Softmax cancels the per-row (w.q_i + b) constant -> weights depend only on keys:
//   out[i] = prefix_{j<=i}(e_j * v_j) / prefix_{j<=i}(e_j),  e_j = exp(-(w.k_j)/8).
// Two kernels (rounds 3/5/7: ANY intra-kernel cross-block sync measured 2-12x
// worse than a 2nd launch). Ladder: CS=32 19.7us -> CS=64 17.1us -> CS=128 now.
//   K1: chunk (128 rows) scores + chunk partial sums. Early V loads, NT key loads.
//   K2: wave-strided prefix over predecessors + register V downsweep + NT out.
// 512 blocks x 512 threads (8 waves) -> 2 blocks/CU, 16 waves/CU.

#define B_   4
#define S_   2048
#define H_   8
#define E_   64
#define BH_  (B_ * H_)
#define CS   128                 // rows per chunk (per block)
#define NC   (S_ / CS)           // 16 chunks per (b,h)
#define NBLK (BH_ * NC)          // 512 blocks
#define TPB  512                 // 8 waves
#define WPB  8
#define RPW  16                  // rows per wave in downsweep (CS / WPB)

typedef float v4f __attribute__((ext_vector_type(4)));

// ---------------- K1: scores + chunk partials ----------------
__global__ __launch_bounds__(TPB) void k_part(const float* __restrict__ keys,
                                              const float* __restrict__ values,
                                              const float* __restrict__ w,
                                              float* __restrict__ e_g,
                                              float* __restrict__ cden,
                                              float* __restrict__ cnum) {
    const int blk = blockIdx.x;
    const int bh  = blk / NC, c = blk % NC;
    const int b   = bh / H_,  h = bh % H_;
    const int t   = threadIdx.x, wave = t >> 6, lane = t & 63;
    const int cf  = lane & 15, rq = lane >> 4;
    const int c4  = t & 15,   rg = t >> 4;     // value-load pattern (32 row-groups)

    __shared__ float e_lds[CS];
    __shared__ float red[32][E_];              // row-group partials, 8KB

    const size_t row0 = (size_t)b * S_ + (size_t)c * CS;

    // T14: issue the 4 independent V float4 streams FIRST (latency hides under
    // key dots). Rows rg+32k, float4 column c4. Cached — K2 re-reads them.
    const v4f* vb = reinterpret_cast<const v4f*>(
        values + (row0 * H_ + h) * (size_t)E_) + c4;
    v4f v0 = vb[(size_t)(rg     ) * (H_ * E_ / 4)];
    v4f v1 = vb[(size_t)(rg + 32) * (H_ * E_ / 4)];
    v4f v2 = vb[(size_t)(rg + 64) * (H_ * E_ / 4)];
    v4f v3 = vb[(size_t)(rg + 96) * (H_ * E_ / 4)];

    // scores: wave w covers rows w*16 .. w*16+15; e = exp(-(w.k)/8).
    // Keys are read-once -> non-temporal (preserve L2/L3 for values).
    const float4 w4 = reinterpret_cast<const float4*>(w)[cf];
    const float* kb = keys + (row0 * H_ + h) * (size_t)E_;
    #pragma unroll
    for (int g = 0; g < 4; ++g) {
        const int r = wave * RPW + g * 4 + rq;
        const v4f kv = __builtin_nontemporal_load(
            reinterpret_cast<const v4f*>(kb + (size_t)r * (H_ * E_)) + cf);
        float p = kv.x * w4.x + kv.y * w4.y + kv.z * w4.z + kv.w * w4.w;
        p += __shfl_xor(p, 1);
        p += __shfl_xor(p, 2);
        p += __shfl_xor(p, 4);
        p += __shfl_xor(p, 8);
        if (cf == 0) e_lds[r] = __expf(-p * 0.125f);
    }
    __syncthreads();

    // weighted rows: acc = sum_k e[rg+32k] * vk
    const float e0 = e_lds[rg],      e1 = e_lds[rg + 32];
    const float e2 = e_lds[rg + 64], e3 = e_lds[rg + 96];
    v4f acc;
    acc.x = fmaf(e3, v3.x, fmaf(e2, v2.x, fmaf(e1, v1.x, e0 * v0.x)));
    acc.y = fmaf(e3, v3.y, fmaf(e2, v2.y, fmaf(e1, v1.y, e0 * v0.y)));
    acc.z = fmaf(e3, v3.z, fmaf(e2, v2.z, fmaf(e1, v1.z, e0 * v0.z)));
    acc.w = fmaf(e3, v3.w, fmaf(e2, v2.w, fmaf(e1, v1.w, e0 * v0.w)));
    *reinterpret_cast<v4f*>(&red[rg][c4 * 4]) = acc;

    // den: wave 0 reduces the 128 e values (2 per lane, then 64-lane butterfly)
    if (wave == 0) {
        float d = e_lds[lane] + e_lds[lane + 64];
        d += __shfl_xor(d, 1);
        d += __shfl_xor(d, 2);
        d += __shfl_xor(d, 4);
        d += __shfl_xor(d, 8);
        d += __shfl_xor(d, 16);
        d += __shfl_xor(d, 32);
        if (lane == 0) cden[blk] = d;
    }
    __syncthreads();

    if (t < E_) {                              // channel-wise reduce over 32 rg
        float s = 0.f;
        #pragma unroll
        for (int r2 = 0; r2 < 32; ++r2) s += red[r2][t];
        cnum[(size_t)blk * E_ + t] = s;
    }
    if (t < CS) e_g[(size_t)blk * CS + t] = e_lds[t];
}

// ---------------- K2: prefix + register downsweep + out ----------------
__global__ __launch_bounds__(TPB) void k_scan(const float* __restrict__ values,
                                              const float* __restrict__ e_g,
                                              const float* __restrict__ cden,
                                              const float* __restrict__ cnum,
                                              float* __restrict__ out) {
    const int blk = blockIdx.x;
    const int bh  = blk / NC, c = blk % NC;
    const int b   = bh / H_,  h = bh % H_;
    const int t   = threadIdx.x, wave = t >> 6, lane = t & 63;

    __shared__ float e_lds[CS];
    __shared__ float pnum8[WPB][E_];
    __shared__ float wnum[WPB][E_];
    __shared__ float pd8[WPB], wd[WPB];

    const size_t row0 = (size_t)b * S_ + (size_t)c * CS;

    // T14: issue V (L2/L3-hot, 16-deep queue) + e loads first.
    const float* vp = values + ((row0 + wave * RPW) * H_ + h) * (size_t)E_ + lane;
    float v_r[RPW];
    #pragma unroll
    for (int j = 0; j < RPW; ++j) v_r[j] = vp[(size_t)j * (H_ * E_)];
    if (t < CS) e_lds[t] = e_g[(size_t)blk * CS + t];

    // cross-chunk exclusive prefix, wave-strided over predecessors (L2-hot)
    const int base = bh * NC;
    float pn = 0.f, pd = 0.f;
    for (int cp = wave; cp < c; cp += WPB) {
        pn += cnum[(size_t)(base + cp) * E_ + lane];   // 256B coalesced
        pd += cden[base + cp];                         // uniform
    }
    pnum8[wave][lane] = pn;
    if (lane == 0) pd8[wave] = pd;
    __syncthreads();

    // per-wave partials: wave w owns rows w*16 .. w*16+15
    float num = 0.f, den = 0.f;
    #pragma unroll
    for (int j = 0; j < RPW; ++j) {
        const float e = e_lds[wave * RPW + j];
        num = fmaf(e, v_r[j], num);
        den += e;
    }
    wnum[wave][lane] = num;
    if (lane == 0) wd[wave] = den;
    __syncthreads();

    // combine cross-chunk + cross-wave offsets
    float pnum = 0.f, pden = 0.f;
    #pragma unroll
    for (int i = 0; i < WPB; ++i) { pnum += pnum8[i][lane]; pden += pd8[i]; }
    #pragma unroll
    for (int w2 = 0; w2 < WPB - 1; ++w2) {
        if (w2 < wave) { pnum += wnum[w2][lane]; pden += wd[w2]; }
    }

    // downsweep from registers, NT store (out is write-once)
    float* op = out + ((row0 + wave * RPW) * H_ + h) * (size_t)E_ + lane;  // L==S
    #pragma unroll
    for (int j = 0; j < RPW; ++j) {
        const float e = e_lds[wave * RPW + j];
        pnum = fmaf(e, v_r[j], pnum);
        pden += e;
        __builtin_nontemporal_store(pnum * __builtin_amdgcn_rcpf(pden),
                                    &op[(size_t)j * (H_ * E_)]);
    }
}

extern "C" void kernel_launch(void* const* d_in, const int* in_sizes, int n_in,
                              void* d_out, int out_size, void* d_ws, size_t ws_size,
                              hipStream_t stream) {
    // inputs: 0=queries (UNUSED), 1=keys, 2=values, 3=w_score,
    //         4=b_score (cancels), 5=attn_mask (sentinel -> causal)
    const float* keys   = (const float*)d_in[1];
    const float* values = (const float*)d_in[2];
    const float* w      = (const float*)d_in[3];
    float* out = (float*)d_out;

    // workspace (floats): e_g[NBLK*CS] | cnum[NBLK*E] | cden[NBLK]
    float* e_g  = (float*)d_ws;
    float* cnum = e_g + (size_t)NBLK * CS;
    float* cden = cnum + (size_t)NBLK * E_;

    hipLaunchKernelGGL(k_part, dim3(NBLK), dim3(TPB), 0, stream,
                       keys, values, w, e_g, cden, cnum);
    hipLaunchKernelGGL(k_scan, dim3(NBLK), dim3(TPB), 0, stream,
                       values, e_g, cden, cnum, out);
}